// Round 1
// baseline (21374.023 us; speedup 1.0000x reference)
//
#include <hip/hip_runtime.h>
#include <math.h>

#define TT 2048
#define BB 64
#define II 64
#define HH 512
#define OO 32
#define OCC 8
#define KCAT (HH + II)   // 576 combined state length (rate ++ x)

// d_out layout: output [T,B,32] | output_ctx [T,B,8] | rate_all [T,B,512]
#define OUT1_OFF ((size_t)TT * BB * OO)            // 4194304
#define RATE_OFF (OUT1_OFF + (size_t)TT * BB * OCC) // 5242880

// ---------------------------------------------------------------------------
// Pack Wcat[k][h] (k-major, coalesced in h):
//   rows 0..511   = Wh^T  (Wcat[k][h] = Wh[h][k])
//   rows 512..575 = Wi^T  (Wcat[512+i][h] = Wi[h][i])
// ---------------------------------------------------------------------------
__global__ __launch_bounds__(256) void pack_weights(
    const float* __restrict__ Wh, const float* __restrict__ Wi,
    float* __restrict__ Wcat)
{
    int idx = blockIdx.x * 256 + threadIdx.x;
    if (idx >= KCAT * HH) return;
    int k = idx >> 9;          // 0..575
    int h = idx & (HH - 1);    // 0..511
    float v = (k < HH) ? Wh[h * HH + k] : Wi[h * II + (k - HH)];
    Wcat[idx] = v;
}

// ---------------------------------------------------------------------------
// Recurrent scan: one workgroup per batch element, fp64 state/arithmetic.
// 512 threads = 8 waves. Wave kg owns state slice k in [72*kg, 72*kg+72).
// Thread (kg, lane) accumulates partial dots for 8 columns h = lane + 64u.
// Partials reduced across the 8 waves through LDS each step.
// ---------------------------------------------------------------------------
__global__ __launch_bounds__(512) void rnn_scan(
    const float* __restrict__ x,       // [T,B,I]
    const float* __restrict__ rate0,   // [B,H]
    const float* __restrict__ noise,   // [T,B,H]
    const float* __restrict__ Wcat,    // [576,512] fp32 (pre-packed)
    const float* __restrict__ bi,
    const float* __restrict__ bh,
    float* __restrict__ rate_out)      // [T,B,H] fp32
{
    __shared__ double st[2][KCAT];     // double-buffered state (rate ++ x)
    __shared__ double parts[8 * HH];   // per-wave partial sums

    const int b    = blockIdx.x;
    const int tid  = threadIdx.x;
    const int lane = tid & 63;
    const int kg   = tid >> 6;         // wave id 0..7
    const int k0   = kg * 72;

    // Mimic reference: alpha = float32(0.1); nscale = float32(sqrt(2*sig^2/alpha))
    const double ALPHA_D = (double)0.1f;
    const double SIG     = 1.5 / sqrt(512.0);
    const double NS_D    = (double)(float)sqrt(2.0 * SIG * SIG / 0.1);

    double rd = (double)rate0[b * HH + tid];   // this thread owns h = tid in update phase
    st[0][tid] = rd;
    if (tid < II) st[0][HH + tid] = (double)x[(size_t)b * II + tid];
    const double bias = (double)bi[tid] + (double)bh[tid];

    for (int t = 0; t < TT; ++t) {
        const int cur = t & 1, nxt = cur ^ 1;
        __syncthreads();   // state[cur] fully written; parts free to overwrite

        // early global loads (consumed after the next barrier)
        float nzf = noise[((size_t)t * BB + b) * HH + tid];
        float xf  = 0.f;
        if (tid < II && t + 1 < TT) xf = x[((size_t)(t + 1) * BB + b) * II + tid];

        // ---- dot phase: acc[u] = sum_{k in slice} Wcat[k][lane+64u] * st[k]
        double acc[8] = {0, 0, 0, 0, 0, 0, 0, 0};
        const float* wp = Wcat + (size_t)k0 * HH + lane;
        #pragma unroll 4
        for (int k = k0; k < k0 + 72; ++k) {
            double s = st[cur][k];             // LDS broadcast (same addr per wave)
            #pragma unroll
            for (int u = 0; u < 8; ++u)
                acc[u] += (double)wp[u * 64] * s;
            wp += HH;
        }
        #pragma unroll
        for (int u = 0; u < 8; ++u)
            parts[kg * HH + lane + u * 64] = acc[u];   // word-stride 2*lane: 2-way, free

        __syncthreads();   // partials complete

        // ---- reduce + update phase: thread tid owns h = tid
        double sum = 0.0;
        #pragma unroll
        for (int g = 0; g < 8; ++g) sum += parts[g * HH + tid];

        double pre = sum + bias + (double)nzf * NS_D;
        rd = (1.0 - ALPHA_D) * rd + ALPHA_D * tanh(pre);

        rate_out[((size_t)t * BB + b) * HH + tid] = (float)rd;
        st[nxt][tid] = rd;
        if (tid < II && t + 1 < TT) st[nxt][HH + tid] = (double)xf;
    }
}

// ---------------------------------------------------------------------------
// Readouts: output = rate_all @ Wo^T + bo ; output_ctx = rate_all @ Woc^T + boc
// One 64-lane group per row (t*B+b); lanes 0..39 each compute one output.
// ---------------------------------------------------------------------------
__global__ __launch_bounds__(256) void readout(
    const float* __restrict__ rate_all,
    const float* __restrict__ Wo,  const float* __restrict__ bo,
    const float* __restrict__ Woc, const float* __restrict__ boc,
    float* __restrict__ out, float* __restrict__ outc)
{
    const int row  = blockIdx.x * 4 + (threadIdx.x >> 6);
    const int lane = threadIdx.x & 63;
    const float* r = rate_all + (size_t)row * HH;
    if (lane < OO + OCC) {
        const float* w = (lane < OO) ? (Wo + (size_t)lane * HH)
                                     : (Woc + (size_t)(lane - OO) * HH);
        float acc = 0.f;
        #pragma unroll 8
        for (int h = 0; h < HH; ++h) acc += r[h] * w[h];
        if (lane < OO) out[(size_t)row * OO + lane] = acc + bo[lane];
        else           outc[(size_t)row * OCC + (lane - OO)] = acc + boc[lane - OO];
    }
}

// ---------------------------------------------------------------------------
extern "C" void kernel_launch(void* const* d_in, const int* in_sizes, int n_in,
                              void* d_out, int out_size, void* d_ws, size_t ws_size,
                              hipStream_t stream)
{
    const float* x     = (const float*)d_in[0];
    const float* rate0 = (const float*)d_in[1];
    const float* noise = (const float*)d_in[2];
    const float* Wi    = (const float*)d_in[3];
    const float* bi    = (const float*)d_in[4];
    const float* Wh    = (const float*)d_in[5];
    const float* bh    = (const float*)d_in[6];
    const float* Wo    = (const float*)d_in[7];
    const float* bo    = (const float*)d_in[8];
    const float* Woc   = (const float*)d_in[9];
    const float* boc   = (const float*)d_in[10];

    float* out  = (float*)d_out;
    float* Wcat = (float*)d_ws;   // 576*512 fp32 = 1.125 MB

    pack_weights<<<(KCAT * HH + 255) / 256, 256, 0, stream>>>(Wh, Wi, Wcat);
    rnn_scan<<<BB, HH, 0, stream>>>(x, rate0, noise, Wcat, bi, bh, out + RATE_OFF);
    readout<<<(TT * BB) / 4, 256, 0, stream>>>(out + RATE_OFF, Wo, bo, Woc, boc,
                                               out, out + OUT1_OFF);
}

// Round 2
// 20233.009 us; speedup vs baseline: 1.0564x; 1.0564x over previous
//
#include <hip/hip_runtime.h>
#include <math.h>

#define TT 2048
#define BB 64
#define II 64
#define HH 512
#define OO 32
#define OCC 8
#define KCAT (HH + II)   // 576 combined state length (rate ++ x)

// d_out layout: output [T,B,32] | output_ctx [T,B,8] | rate_all [T,B,512]
#define OUT1_OFF ((size_t)TT * BB * OO)
#define RATE_OFF (OUT1_OFF + (size_t)TT * BB * OCC)

// ---------------------------------------------------------------------------
// Pack Wcat[k][h] (k-major, coalesced in h):
//   rows 0..511   = Wh^T  (Wcat[k][h] = Wh[h][k])
//   rows 512..575 = Wi^T  (Wcat[512+i][h] = Wi[h][i])
// ---------------------------------------------------------------------------
__global__ __launch_bounds__(256) void pack_weights(
    const float* __restrict__ Wh, const float* __restrict__ Wi,
    float* __restrict__ Wcat)
{
    int idx = blockIdx.x * 256 + threadIdx.x;
    if (idx >= KCAT * HH) return;
    int k = idx >> 9;
    int h = idx & (HH - 1);
    float v = (k < HH) ? Wh[h * HH + k] : Wi[h * II + (k - HH)];
    Wcat[idx] = v;
}

// ---------------------------------------------------------------------------
// Recurrent scan: one 1024-thread WG per batch element (16 waves/CU).
// Wave wv = (kg, hg): kg in 0..7 owns k-slice [72*kg, 72*kg+72);
//                     hg in 0..1 owns h-half [256*hg, 256*hg+256).
// Thread handles 4 CONTIGUOUS h-columns: h = hg*256 + lane*4 .. +4
//   -> one global_load_dwordx4 per k (fully coalesced: wave reads 1KB run).
// Partials parts[kg][h] (8 x 512 doubles = 32KB) reduced by threads tid<512.
// ---------------------------------------------------------------------------
__global__ __launch_bounds__(1024) void rnn_scan(
    const float* __restrict__ x,       // [T,B,I]
    const float* __restrict__ rate0,   // [B,H]
    const float* __restrict__ noise,   // [T,B,H]
    const float* __restrict__ Wcat,    // [576,512] fp32 (pre-packed)
    const float* __restrict__ bi,
    const float* __restrict__ bh,
    float* __restrict__ rate_out)      // [T,B,H] fp32
{
    __shared__ double st[2][KCAT];     // double-buffered state (rate ++ x)
    __shared__ double parts[8 * HH];   // per-kg partial sums

    const int b    = blockIdx.x;
    const int tid  = threadIdx.x;
    const int lane = tid & 63;
    const int wv   = tid >> 6;         // 0..15
    const int kg   = wv >> 1;          // 0..7
    const int hg   = wv & 1;           // 0..1
    const int k0   = kg * 72;
    const int hbase = hg * 256 + lane * 4;

    // Mimic reference: alpha = float32(0.1); nscale = float32(sqrt(2*sig^2/alpha))
    const double ALPHA_D = (double)0.1f;
    const double SIG     = 1.5 / sqrt(512.0);
    const double NS_D    = (double)(float)sqrt(2.0 * SIG * SIG / 0.1);

    double rd = 0.0, bias = 0.0;
    if (tid < HH) {
        rd = (double)rate0[b * HH + tid];
        st[0][tid] = rd;
        bias = (double)bi[tid] + (double)bh[tid];
    } else if (tid < HH + II) {
        st[0][HH + (tid - HH)] = (double)x[(size_t)b * II + (tid - HH)];
    }

    for (int t = 0; t < TT; ++t) {
        const int cur = t & 1, nxt = cur ^ 1;
        __syncthreads();   // st[cur] complete; parts consumed -> reusable

        // early global loads (consumed after the mid barrier)
        float nzf = 0.f, xf = 0.f;
        if (tid < HH) nzf = noise[((size_t)t * BB + b) * HH + tid];
        else if (tid < HH + II && t + 1 < TT)
            xf = x[((size_t)(t + 1) * BB + b) * II + (tid - HH)];

        // ---- dot phase: acc[j] = sum_{k in slice} Wcat[k][hbase+j] * st[k]
        double a0 = 0.0, a1 = 0.0, a2 = 0.0, a3 = 0.0;
        const float* wp = Wcat + (size_t)k0 * HH + hbase;
        #pragma unroll 4
        for (int kk = 0; kk < 36; ++kk) {          // 2 k's per iteration
            double2 s2 = *(const double2*)&st[cur][k0 + 2 * kk];
            float4 w0 = *(const float4*)(wp);
            float4 w1 = *(const float4*)(wp + HH);
            a0 += (double)w0.x * s2.x + (double)w1.x * s2.y;
            a1 += (double)w0.y * s2.x + (double)w1.y * s2.y;
            a2 += (double)w0.z * s2.x + (double)w1.z * s2.y;
            a3 += (double)w0.w * s2.x + (double)w1.w * s2.y;
            wp += 2 * HH;
        }
        {
            double2* pw = (double2*)&parts[kg * HH + hbase];
            pw[0] = make_double2(a0, a1);
            pw[1] = make_double2(a2, a3);
        }

        __syncthreads();   // partials complete

        // ---- reduce + update: thread tid (<512) owns h = tid
        if (tid < HH) {
            double sum = 0.0;
            #pragma unroll
            for (int g = 0; g < 8; ++g) sum += parts[g * HH + tid];
            double pre = sum + bias + (double)nzf * NS_D;
            rd = (1.0 - ALPHA_D) * rd + ALPHA_D * tanh(pre);
            rate_out[((size_t)t * BB + b) * HH + tid] = (float)rd;
            st[nxt][tid] = rd;
        } else if (tid < HH + II && t + 1 < TT) {
            st[nxt][HH + (tid - HH)] = (double)xf;
        }
    }
}

// ---------------------------------------------------------------------------
// Readouts: 8 rows per 256-thread block, rows staged in LDS, float4 dots.
// Thread (r = tid>>5, o = tid&31) computes output[row0+r][o];
// threads 0..63 additionally compute the 8-wide ctx readout.
// ---------------------------------------------------------------------------
__global__ __launch_bounds__(256) void readout(
    const float* __restrict__ rate_all,
    const float* __restrict__ Wo,  const float* __restrict__ bo,
    const float* __restrict__ Woc, const float* __restrict__ boc,
    float* __restrict__ out, float* __restrict__ outc)
{
    __shared__ float rbuf[8][HH];
    const int tid  = threadIdx.x;
    const size_t row0 = (size_t)blockIdx.x * 8;

    for (int i = tid; i < 8 * (HH / 4); i += 256) {   // 1024 float4 loads
        int r = i >> 7, c = (i & 127) * 4;
        *(float4*)&rbuf[r][c] = *(const float4*)&rate_all[(row0 + r) * HH + c];
    }
    __syncthreads();

    {
        int r = tid >> 5, o = tid & 31;
        const float* w = Wo + (size_t)o * HH;
        float acc = 0.f;
        #pragma unroll 4
        for (int h = 0; h < HH; h += 4) {
            float4 rv = *(const float4*)&rbuf[r][h];
            float4 wv = *(const float4*)&w[h];
            acc += rv.x * wv.x + rv.y * wv.y + rv.z * wv.z + rv.w * wv.w;
        }
        out[(row0 + r) * OO + o] = acc + bo[o];
    }
    if (tid < 64) {
        int r = tid >> 3, oc = tid & 7;
        const float* w = Woc + (size_t)oc * HH;
        float acc = 0.f;
        #pragma unroll 4
        for (int h = 0; h < HH; h += 4) {
            float4 rv = *(const float4*)&rbuf[r][h];
            float4 wv = *(const float4*)&w[h];
            acc += rv.x * wv.x + rv.y * wv.y + rv.z * wv.z + rv.w * wv.w;
        }
        outc[(row0 + r) * OCC + oc] = acc + boc[oc];
    }
}

// ---------------------------------------------------------------------------
extern "C" void kernel_launch(void* const* d_in, const int* in_sizes, int n_in,
                              void* d_out, int out_size, void* d_ws, size_t ws_size,
                              hipStream_t stream)
{
    const float* x     = (const float*)d_in[0];
    const float* rate0 = (const float*)d_in[1];
    const float* noise = (const float*)d_in[2];
    const float* Wi    = (const float*)d_in[3];
    const float* bi    = (const float*)d_in[4];
    const float* Wh    = (const float*)d_in[5];
    const float* bh    = (const float*)d_in[6];
    const float* Wo    = (const float*)d_in[7];
    const float* bo    = (const float*)d_in[8];
    const float* Woc   = (const float*)d_in[9];
    const float* boc   = (const float*)d_in[10];

    float* out  = (float*)d_out;
    float* Wcat = (float*)d_ws;   // 576*512 fp32 = 1.125 MB

    pack_weights<<<(KCAT * HH + 255) / 256, 256, 0, stream>>>(Wh, Wi, Wcat);
    rnn_scan<<<BB, 1024, 0, stream>>>(x, rate0, noise, Wcat, bi, bh, out + RATE_OFF);
    readout<<<(TT * BB) / 8, 256, 0, stream>>>(out + RATE_OFF, Wo, bo, Woc, boc,
                                               out, out + OUT1_OFF);
}

// Round 3
// 18677.203 us; speedup vs baseline: 1.1444x; 1.0833x over previous
//
#include <hip/hip_runtime.h>
#include <math.h>

#define TT 2048
#define BB 64
#define II 64
#define HH 512
#define OO 32
#define OCC 8
#define KCAT (HH + II)   // 576 combined state length (rate ++ x)

// d_out layout: output [T,B,32] | output_ctx [T,B,8] | rate_all [T,B,512]
#define OUT1_OFF ((size_t)TT * BB * OO)
#define RATE_OFF (OUT1_OFF + (size_t)TT * BB * OCC)

// ---------------------------------------------------------------------------
// Pack Wcat[k][h] (k-major, coalesced in h):
//   rows 0..511   = Wh^T  (Wcat[k][h] = Wh[h][k])
//   rows 512..575 = Wi^T  (Wcat[512+i][h] = Wi[h][i])
// ---------------------------------------------------------------------------
__global__ __launch_bounds__(256) void pack_weights(
    const float* __restrict__ Wh, const float* __restrict__ Wi,
    float* __restrict__ Wcat)
{
    int idx = blockIdx.x * 256 + threadIdx.x;
    if (idx >= KCAT * HH) return;
    int k = idx >> 9;
    int h = idx & (HH - 1);
    float v = (k < HH) ? Wh[h * HH + k] : Wi[h * II + (k - HH)];
    Wcat[idx] = v;
}

// ---------------------------------------------------------------------------
// Recurrent scan, FP32: one 1024-thread WG per batch element.
// Wave wv = (kg, hg): kg in 0..7 owns k-slice [72*kg, 72*kg+72);
//                     hg in 0..1 owns h-half [256*hg, 256*hg+256).
// Thread handles 4 contiguous h: one global_load_dwordx4 per k (coalesced).
// Partials parts[kg][h] (8 x 512 fp32 = 16KB) reduced by threads tid<512.
// fp32 recurrence matches the rounding class of the harness's fp32 reference.
// ---------------------------------------------------------------------------
__global__ __launch_bounds__(1024) void rnn_scan(
    const float* __restrict__ x,       // [T,B,I]
    const float* __restrict__ rate0,   // [B,H]
    const float* __restrict__ noise,   // [T,B,H]
    const float* __restrict__ Wcat,    // [576,512] fp32 (pre-packed)
    const float* __restrict__ bi,
    const float* __restrict__ bh,
    float* __restrict__ rate_out)      // [T,B,H] fp32
{
    __shared__ float st[2][KCAT];      // double-buffered state (rate ++ x)
    __shared__ float parts[8 * HH];    // per-kg partial sums

    const int b    = blockIdx.x;
    const int tid  = threadIdx.x;
    const int lane = tid & 63;
    const int wv   = tid >> 6;         // 0..15
    const int kg   = wv >> 1;          // 0..7
    const int hg   = wv & 1;           // 0..1
    const int k0   = kg * 72;
    const int hbase = hg * 256 + lane * 4;

    // float32(0.1): 1-a and 0.9f are bit-identical (0x3F666666), so plain
    // 0.9f/0.1f literals reproduce the reference blend exactly.
    const double SIG = 1.5 / sqrt(512.0);
    const float  NS  = (float)sqrt(2.0 * SIG * SIG / 0.1);

    float rf = 0.f, bias = 0.f;
    if (tid < HH) {
        rf = rate0[b * HH + tid];
        st[0][tid] = rf;
        bias = bi[tid] + bh[tid];
    } else if (tid < HH + II) {
        st[0][HH + (tid - HH)] = x[(size_t)b * II + (tid - HH)];
    }

    for (int t = 0; t < TT; ++t) {
        const int cur = t & 1, nxt = cur ^ 1;
        __syncthreads();   // st[cur] complete; parts consumed -> reusable

        // early global loads (consumed after the mid barrier; HBM latency
        // hides under the ~5000-cycle dot phase)
        float nzf = 0.f, xf = 0.f;
        if (tid < HH) nzf = noise[((size_t)t * BB + b) * HH + tid];
        else if (tid < HH + II && t + 1 < TT)
            xf = x[((size_t)(t + 1) * BB + b) * II + (tid - HH)];

        // ---- dot phase: acc[j] = sum_{k in slice} Wcat[k][hbase+j] * st[k]
        float a0 = 0.f, a1 = 0.f, a2 = 0.f, a3 = 0.f;
        const float* wp = Wcat + (size_t)k0 * HH + hbase;
        #pragma unroll 6
        for (int kk = 0; kk < 18; ++kk) {          // 4 k's per iteration
            float4 s4 = *(const float4*)&st[cur][k0 + 4 * kk];  // uniform b128
            float4 w0 = *(const float4*)(wp);
            float4 w1 = *(const float4*)(wp + HH);
            float4 w2 = *(const float4*)(wp + 2 * HH);
            float4 w3 = *(const float4*)(wp + 3 * HH);
            a0 += w0.x * s4.x; a1 += w0.y * s4.x; a2 += w0.z * s4.x; a3 += w0.w * s4.x;
            a0 += w1.x * s4.y; a1 += w1.y * s4.y; a2 += w1.z * s4.y; a3 += w1.w * s4.y;
            a0 += w2.x * s4.z; a1 += w2.y * s4.z; a2 += w2.z * s4.z; a3 += w2.w * s4.z;
            a0 += w3.x * s4.w; a1 += w3.y * s4.w; a2 += w3.z * s4.w; a3 += w3.w * s4.w;
            wp += 4 * HH;
        }
        *(float4*)&parts[kg * HH + hbase] = make_float4(a0, a1, a2, a3);

        __syncthreads();   // partials complete

        // ---- reduce + update: thread tid (<512) owns h = tid
        if (tid < HH) {
            float sum = 0.f;
            #pragma unroll
            for (int g = 0; g < 8; ++g) sum += parts[g * HH + tid];
            float pre = sum + bias + nzf * NS;
            rf = 0.9f * rf + 0.1f * tanhf(pre);
            rate_out[((size_t)t * BB + b) * HH + tid] = rf;
            st[nxt][tid] = rf;
        } else if (tid < HH + II && t + 1 < TT) {
            st[nxt][HH + (tid - HH)] = xf;
        }
    }
}

// ---------------------------------------------------------------------------
// Readouts: 8 rows per 256-thread block, rows staged in LDS, float4 dots.
// ---------------------------------------------------------------------------
__global__ __launch_bounds__(256) void readout(
    const float* __restrict__ rate_all,
    const float* __restrict__ Wo,  const float* __restrict__ bo,
    const float* __restrict__ Woc, const float* __restrict__ boc,
    float* __restrict__ out, float* __restrict__ outc)
{
    __shared__ float rbuf[8][HH];
    const int tid  = threadIdx.x;
    const size_t row0 = (size_t)blockIdx.x * 8;

    for (int i = tid; i < 8 * (HH / 4); i += 256) {
        int r = i >> 7, c = (i & 127) * 4;
        *(float4*)&rbuf[r][c] = *(const float4*)&rate_all[(row0 + r) * HH + c];
    }
    __syncthreads();

    {
        int r = tid >> 5, o = tid & 31;
        const float* w = Wo + (size_t)o * HH;
        float acc = 0.f;
        #pragma unroll 4
        for (int h = 0; h < HH; h += 4) {
            float4 rv = *(const float4*)&rbuf[r][h];
            float4 wv = *(const float4*)&w[h];
            acc += rv.x * wv.x + rv.y * wv.y + rv.z * wv.z + rv.w * wv.w;
        }
        out[(row0 + r) * OO + o] = acc + bo[o];
    }
    if (tid < 64) {
        int r = tid >> 3, oc = tid & 7;
        const float* w = Woc + (size_t)oc * HH;
        float acc = 0.f;
        #pragma unroll 4
        for (int h = 0; h < HH; h += 4) {
            float4 rv = *(const float4*)&rbuf[r][h];
            float4 wv = *(const float4*)&w[h];
            acc += rv.x * wv.x + rv.y * wv.y + rv.z * wv.z + rv.w * wv.w;
        }
        outc[(row0 + r) * OCC + oc] = acc + boc[oc];
    }
}

// ---------------------------------------------------------------------------
extern "C" void kernel_launch(void* const* d_in, const int* in_sizes, int n_in,
                              void* d_out, int out_size, void* d_ws, size_t ws_size,
                              hipStream_t stream)
{
    const float* x     = (const float*)d_in[0];
    const float* rate0 = (const float*)d_in[1];
    const float* noise = (const float*)d_in[2];
    const float* Wi    = (const float*)d_in[3];
    const float* bi    = (const float*)d_in[4];
    const float* Wh    = (const float*)d_in[5];
    const float* bh    = (const float*)d_in[6];
    const float* Wo    = (const float*)d_in[7];
    const float* bo    = (const float*)d_in[8];
    const float* Woc   = (const float*)d_in[9];
    const float* boc   = (const float*)d_in[10];

    float* out  = (float*)d_out;
    float* Wcat = (float*)d_ws;   // 576*512 fp32 = 1.125 MB

    pack_weights<<<(KCAT * HH + 255) / 256, 256, 0, stream>>>(Wh, Wi, Wcat);
    rnn_scan<<<BB, 1024, 0, stream>>>(x, rate0, noise, Wcat, bi, bh, out + RATE_OFF);
    readout<<<(TT * BB) / 8, 256, 0, stream>>>(out + RATE_OFF, Wo, bo, Woc, boc,
                                               out, out + OUT1_OFF);
}